// Round 14
// baseline (159.988 us; speedup 1.0000x reference)
//
#include <hip/hip_runtime.h>
#include <hip/hip_bf16.h>

#define DEV __device__ __forceinline__

#define BATCH 2
#define SEQ   2048
#define DMODEL 1024
#define NHEAD 16
#define DK    64
#define MROWS (BATCH*SEQ)   // 4096
#define KD    1024
#define GEMM_NT (KD/32)     // 32 K-iterations

// q-projection scale: (1/sqrt(dk)) * log2(e)  -> scores arrive in exp2 domain
#define QSCALE 0.18033688011112042f

typedef __attribute__((ext_vector_type(4))) float f32x4;
typedef __attribute__((ext_vector_type(8))) short s16x8;
typedef __attribute__((ext_vector_type(4))) float fvec4;
typedef __attribute__((ext_vector_type(2))) unsigned int u32x2;
typedef __attribute__((ext_vector_type(4))) unsigned int u32x4;

// ---------------- scratch (device globals) ---------------------------------
__device__ short g_X[3][MROWS*DMODEL];   // bf16 Q,K,V inputs
__device__ short g_W[4][DMODEL*DMODEL];  // bf16 Wq,Wk,Wv,Wo
__device__ short g_q [MROWS*DMODEL];     // [B,H,S,dk], pre-scaled by QSCALE
__device__ short g_k [MROWS*DMODEL];     // [B,H,S,dk]
__device__ short g_vt[MROWS*DMODEL];     // [B,H,dk,S]
__device__ short g_at[MROWS*DMODEL];     // attention out [B,S,D]

DEV short f2bf(float f) {
  union { __hip_bfloat16 h; short s; } u;
  u.h = __float2bfloat16(f);
  return u.s;
}

// HW RNE pack of two f32 -> two bf16 in one u32 (lo bits 15:0, hi 31:16)
DEV unsigned int f2bf2(float lo, float hi) {
  unsigned int r;
  asm("v_cvt_pk_bf16_f32 %0, %1, %2" : "=v"(r) : "v"(lo), "v"(hi));
  return r;
}

// single-instruction 2^x (avoids OCML multi-inst denormal path; R12-proven)
DEV float fexp2(float x) {
  float r;
  asm("v_exp_f32 %0, %1" : "=v"(r) : "v"(x));
  return r;
}

DEV void gload_lds16(const void* g, void* l) {
  __builtin_amdgcn_global_load_lds(
      (const __attribute__((address_space(1))) void*)g,
      (__attribute__((address_space(3))) void*)l, 16, 0, 0);
}

DEV f32x4 mfma16(s16x8 a, s16x8 b, f32x4 c) {
  return __builtin_amdgcn_mfma_f32_16x16x32_bf16(a, b, c, 0, 0, 0);
}

// ---------------- fused fp32 -> bf16 cast (all 7 tensors, one launch) -------
__global__ __launch_bounds__(256)
void cast_all(const float* __restrict__ q, const float* __restrict__ k,
              const float* __restrict__ v, const float* __restrict__ wq,
              const float* __restrict__ wk, const float* __restrict__ wv,
              const float* __restrict__ wo) {
  int z = blockIdx.z;
  const float* src;
  short* dst;
  int n8;
  if (z < 3) {
    src = z == 0 ? q : z == 1 ? k : v;
    dst = g_X[z];
    n8 = MROWS*DMODEL/8;
  } else {
    src = z == 3 ? wq : z == 4 ? wk : z == 5 ? wv : wo;
    dst = g_W[z - 3];
    n8 = DMODEL*DMODEL/8;
  }
  int i = blockIdx.x * 256 + threadIdx.x;
  if (i < n8) {
    const fvec4* p = (const fvec4*)(src + (size_t)i*8);
    fvec4 v0 = p[0], v1 = p[1];
    u32x4 r;
    r[0] = f2bf2(v0[0], v0[1]); r[1] = f2bf2(v0[2], v0[3]);
    r[2] = f2bf2(v1[0], v1[1]); r[3] = f2bf2(v1[2], v1[3]);
    *(u32x4*)(dst + (size_t)i*8) = r;
  }
}

// ---------------- GEMM core: 128(M)x64(N) tile, 24 KB LDS, 6 blocks/CU ------
// 4 waves; wave w owns rows [w*32, w*32+32) x all 64 cols: acc[2][4],
// 2 A-frags + 4 B-frags -> 8 MFMA/iter. Stage = 3 gload16/thread (A 8KB,
// B 4KB). Counted vmcnt(3): stage i done, stage i+1 in flight. Two barriers
// per iter; stage(i+2) overwrites the buffer just read (WAR-safe after bar2).
struct GemmSmem { short As[2][128*32]; short Bs[2][64*32]; };  // 24 KB

DEV void gemm_core(GemmSmem& sm, const short* __restrict__ A,
                   const short* __restrict__ Bw, const float* __restrict__ bias,
                   void* __restrict__ outp, float scale, int mode,
                   int rowBase, int colBase) {
  const int t = threadIdx.x, l = t & 63, w = t >> 6, g = l >> 4;

  f32x4 acc[2][4] = {};

  auto stage = [&](int buf, int k0) {
#pragma unroll
    for (int j = 0; j < 2; ++j) {          // A tile: 128x32
      int e = w*1024 + j*512 + l*8;
      int e2 = e ^ (((e >> 7) & 3) << 3);
      gload_lds16(A + (size_t)(rowBase + (e2 >> 5))*KD + k0 + (e2 & 31),
                  &sm.As[buf][w*1024 + j*512]);
    }
    {                                       // B tile: 64x32
      int e = t*8;
      int e2 = e ^ (((e >> 7) & 3) << 3);
      gload_lds16(Bw + (size_t)(colBase + (e2 >> 5))*KD + k0 + (e2 & 31),
                  &sm.Bs[buf][t*8]);
    }
  };

  stage(0, 0);
  stage(1, 32);

  for (int i = 0; i < GEMM_NT; ++i) {
    if (i < GEMM_NT - 1) asm volatile("s_waitcnt vmcnt(3)" ::: "memory");
    else                 asm volatile("s_waitcnt vmcnt(0)" ::: "memory");
    __builtin_amdgcn_s_barrier();
    __builtin_amdgcn_sched_barrier(0);

    const int cur = i & 1;
    s16x8 a[2], b[4];
#pragma unroll
    for (int x = 0; x < 2; ++x) {
      int ra = w*32 + x*16 + (l & 15);
      int ia = (ra*32 + g*8) ^ (((ra >> 2) & 3) << 3);
      a[x] = *(const s16x8*)&sm.As[cur][ia];
    }
#pragma unroll
    for (int jn = 0; jn < 4; ++jn) {
      int rb = jn*16 + (l & 15);
      int ib = (rb*32 + g*8) ^ (((rb >> 2) & 3) << 3);
      b[jn] = *(const s16x8*)&sm.Bs[cur][ib];
    }

    __builtin_amdgcn_s_setprio(1);
#pragma unroll
    for (int x = 0; x < 2; ++x)
#pragma unroll
      for (int jn = 0; jn < 4; ++jn)
        acc[x][jn] = mfma16(a[x], b[jn], acc[x][jn]);
    __builtin_amdgcn_s_setprio(0);

    __builtin_amdgcn_s_barrier();      // all waves done reading buf[cur]
    __builtin_amdgcn_sched_barrier(0);
    if (i + 2 < GEMM_NT) stage(cur, (i + 2)*32);   // overwrite buf just read
  }

#pragma unroll
  for (int x = 0; x < 2; ++x) {
    int mrow0 = rowBase + w*32 + x*16 + g*4;
#pragma unroll
    for (int jn = 0; jn < 4; ++jn) {
      int n = colBase + jn*16 + (l & 15);
      float bv = bias[n];
      float val[4];
#pragma unroll
      for (int r = 0; r < 4; ++r) val[r] = (acc[x][jn][r] + bv) * scale;
      if (mode == 3) {
#pragma unroll
        for (int r = 0; r < 4; ++r)
          ((float*)outp)[(size_t)(mrow0 + r)*DMODEL + n] = val[r];
      } else {
        unsigned int pk0 = f2bf2(val[0], val[1]);
        unsigned int pk1 = f2bf2(val[2], val[3]);
        int h = n >> 6, d = n & 63;
#pragma unroll
        for (int r = 0; r < 4; ++r) {
          int m = mrow0 + r;
          int b = m >> 11, s = m & 2047;
          unsigned int pk = r < 2 ? pk0 : pk1;
          short sv = (short)((r & 1) ? (pk >> 16) : (pk & 0xffff));
          if (mode == 1)
            ((short*)outp)[(((size_t)(b*NHEAD + h)*SEQ + s)*DK) + d] = sv;
          else
            ((short*)outp)[((size_t)(b*NHEAD + h)*DK + d)*SEQ + s] = sv;
        }
      }
    }
  }
}

// grid (16, 32, 3) = 1536 blocks = 6/CU
__global__ __launch_bounds__(256, 6)
void proj_qkv(const float* __restrict__ bq, const float* __restrict__ bk,
              const float* __restrict__ bv) {
  __shared__ GemmSmem sm;
  int z = blockIdx.z;
  int orig = blockIdx.y*16 + blockIdx.x;        // [0,512)
  int swz = (orig & 7)*64 + (orig >> 3);        // XCD-chunked, bijective
  int bx = swz & 15, by = swz >> 4;
  const float* bias = z == 0 ? bq : z == 1 ? bk : bv;
  void* outp = z == 0 ? (void*)g_q : z == 1 ? (void*)g_k : (void*)g_vt;
  gemm_core(sm, g_X[z], g_W[z], bias, outp, z == 0 ? QSCALE : 1.0f,
            z == 2 ? 2 : 1, by*128, bx*64);
}

__global__ __launch_bounds__(256, 6)
void proj_out(const float* __restrict__ bo, float* __restrict__ out) {
  __shared__ GemmSmem sm;
  int orig = blockIdx.y*16 + blockIdx.x;
  int swz = (orig & 7)*64 + (orig >> 3);
  int bx = swz & 15, by = swz >> 4;
  gemm_core(sm, g_at, g_W[3], bo, out, 1.0f, 3, by*128, bx*64);
}

// ---------------- flash attention (unchanged from R12/R13) ------------------
// split-K: 8 waves, wave w owns q-rows (w&3)*32..+32 over k-tile parity w>>2.
// 4-buffer K/V ring, counted waits, permlane P-rebuild, v_exp_f32 softmax.
__global__ __launch_bounds__(512, 4)
void attn_kernel(short* __restrict__ aout) {
  __shared__ short ks[4][64*64];    // 32 KB (combine: lsum area after loop)
  __shared__ short vs[4][64*64];    // 32 KB (combine: o area after loop)

  const int t = threadIdx.x, l = t & 63, w = t >> 6, g = l >> 4;
  const int q15 = l & 15;
  const int qg = w & 3, kp = w >> 2;
  int orig = blockIdx.y*16 + blockIdx.x;     // 512 blocks, %8==0
  int swz = (orig & 7)*64 + (orig >> 3);     // XCD-chunked, bijective
  const int qblk = swz & 15, bh = swz >> 4;
  const int qbase = qblk * 128;
  const size_t hoff = (size_t)bh * SEQ * DK;

  auto stage_pair = [&](int pr) {
    int e = t*8;                               // 512 thr x 8 shorts = one tile
    int e2 = e ^ (((e >> 6) & 7) << 3);
    int t0 = 2*pr, t1 = t0 + 1;
    gload_lds16(g_k + hoff + (size_t)(t0*64)*DK + e2, &ks[t0 & 3][e]);
    gload_lds16(g_k + hoff + (size_t)(t1*64)*DK + e2, &ks[t1 & 3][e]);
    gload_lds16(g_vt + hoff + (size_t)(e2 >> 6)*SEQ + t0*64 + (e2 & 63), &vs[t0 & 3][e]);
    gload_lds16(g_vt + hoff + (size_t)(e2 >> 6)*SEQ + t1*64 + (e2 & 63), &vs[t1 & 3][e]);
  };

  s16x8 qf[2][2];
  {
    const short* q0 = g_q + hoff + (size_t)(qbase + qg*32 + q15)*DK;
    qf[0][0] = *(const s16x8*)(q0 + g*8);
    qf[0][1] = *(const s16x8*)(q0 + 32 + g*8);
    qf[1][0] = *(const s16x8*)(q0 + 16*DK + g*8);
    qf[1][1] = *(const s16x8*)(q0 + 16*DK + 32 + g*8);
  }
  stage_pair(0);

  float lsum[2] = {0.f, 0.f};
  f32x4 o[2][4] = {};

  for (int i = 0; i < 16; ++i) {
    asm volatile("s_waitcnt vmcnt(0)" ::: "memory");
    __builtin_amdgcn_s_barrier();
    __builtin_amdgcn_sched_barrier(0);
    if (i + 1 < 16) stage_pair(i + 1);   // targets pair i-1's buffers (safe)

    const short* kb = ks[(2*i + kp) & 3];
    const short* vb = vs[(2*i + kp) & 3];

    f32x4 sc[2][4] = {};
    __builtin_amdgcn_s_setprio(1);
#pragma unroll
    for (int ni = 0; ni < 4; ++ni) {
      int row = ni*16 + q15;
      int sx = (row & 7) << 3;
      s16x8 k0 = *(const s16x8*)&kb[(row*64 + g*8) ^ sx];
      s16x8 k1 = *(const s16x8*)&kb[(row*64 + 32 + g*8) ^ sx];
      sc[0][ni] = mfma16(k0, qf[0][0], sc[0][ni]);
      sc[0][ni] = mfma16(k1, qf[0][1], sc[0][ni]);
      sc[1][ni] = mfma16(k0, qf[1][0], sc[1][ni]);
      sc[1][ni] = mfma16(k1, qf[1][1], sc[1][ni]);
    }
    __builtin_amdgcn_s_setprio(0);

    s16x8 pa[2][2];
#pragma unroll
    for (int grp = 0; grp < 2; ++grp) {
      float p[4][4];
#pragma unroll
      for (int ni = 0; ni < 4; ++ni)
#pragma unroll
        for (int r = 0; r < 4; ++r)
          p[ni][r] = fexp2(sc[grp][ni][r]);
      float s0 = (p[0][0]+p[0][1]) + (p[0][2]+p[0][3]);
      float s1 = (p[1][0]+p[1][1]) + (p[1][2]+p[1][3]);
      float s2 = (p[2][0]+p[2][1]) + (p[2][2]+p[2][3]);
      float s3 = (p[3][0]+p[3][1]) + (p[3][2]+p[3][3]);
      lsum[grp] += (s0+s1) + (s2+s3);

      unsigned pk[4][2];
#pragma unroll
      for (int ni = 0; ni < 4; ++ni) {
        pk[ni][0] = f2bf2(p[ni][0], p[ni][1]);
        pk[ni][1] = f2bf2(p[ni][2], p[ni][3]);
      }
#pragma unroll
      for (int kf = 0; kf < 2; ++kf) {
        u32x4 P4;
#pragma unroll
        for (int u = 0; u < 2; ++u) {
          unsigned x = pk[2*kf][u], y = pk[2*kf + 1][u];
          asm("v_permlane32_swap_b32 %0, %1" : "+v"(x), "+v"(y));
          asm("v_permlane16_swap_b32 %0, %1" : "+v"(x), "+v"(y));
          P4[u]     = x;
          P4[2 + u] = y;
        }
        union { u32x4 u4; s16x8 s8; } cv;
        cv.u4 = P4;
        pa[grp][kf] = cv.s8;
      }
    }

    __builtin_amdgcn_s_setprio(1);
#pragma unroll
    for (int nd = 0; nd < 4; ++nd) {
      int row = nd*16 + q15;
      int sx = (row & 7) << 3;
      s16x8 v0 = *(const s16x8*)&vb[(row*64 + g*8) ^ sx];
      s16x8 v1 = *(const s16x8*)&vb[(row*64 + 32 + g*8) ^ sx];
      o[0][nd] = mfma16(pa[0][0], v0, o[0][nd]);
      o[0][nd] = mfma16(pa[0][1], v1, o[0][nd]);
      o[1][nd] = mfma16(pa[1][0], v0, o[1][nd]);
      o[1][nd] = mfma16(pa[1][1], v1, o[1][nd]);
    }
    __builtin_amdgcn_s_setprio(0);
  }

  // ---- split-K combine ----
  __syncthreads();
  float* ob = (float*)&vs[0][0];
  float* lb = (float*)&ks[0][0];
  if (kp) {
#pragma unroll
    for (int grp = 0; grp < 2; ++grp) {
#pragma unroll
      for (int nd = 0; nd < 4; ++nd)
#pragma unroll
        for (int r = 0; r < 4; ++r)
          ob[(qg*32 + grp*16 + nd*4 + r)*64 + l] = o[grp][nd][r];
      lb[(qg*2 + grp)*64 + l] = lsum[grp];
    }
  }
  __syncthreads();
  if (!kp) {
    int b = bh >> 4, h = bh & 15;
#pragma unroll
    for (int grp = 0; grp < 2; ++grp) {
#pragma unroll
      for (int nd = 0; nd < 4; ++nd)
#pragma unroll
        for (int r = 0; r < 4; ++r)
          o[grp][nd][r] += ob[(qg*32 + grp*16 + nd*4 + r)*64 + l];
      float ls = lsum[grp] + lb[(qg*2 + grp)*64 + l];
      ls += __shfl_xor(ls, 16);
      ls += __shfl_xor(ls, 32);
      float inv = 1.0f / ls;
      float iv[4];
#pragma unroll
      for (int r = 0; r < 4; ++r)
        iv[r] = __shfl(inv, (l & 48) | (g*4 + r));
#pragma unroll
      for (int nd = 0; nd < 4; ++nd) {
        int dcol = h*DK + nd*16 + q15;
#pragma unroll
        for (int r = 0; r < 4; ++r) {
          int srow = qbase + qg*32 + grp*16 + g*4 + r;
          aout[((size_t)(b*SEQ + srow))*DMODEL + dcol] = f2bf(o[grp][nd][r] * iv[r]);
        }
      }
    }
  }
}

// ---------------- host side -------------------------------------------------
extern "C" void kernel_launch(void* const* d_in, const int* in_sizes, int n_in,
                              void* d_out, int out_size, void* d_ws, size_t ws_size,
                              hipStream_t stream) {
  const float* Q  = (const float*)d_in[0];
  const float* K  = (const float*)d_in[1];
  const float* V  = (const float*)d_in[2];
  const float* Wq = (const float*)d_in[3];
  const float* bq = (const float*)d_in[4];
  const float* Wk = (const float*)d_in[5];
  const float* bk = (const float*)d_in[6];
  const float* Wv = (const float*)d_in[7];
  const float* bv = (const float*)d_in[8];
  const float* Wo = (const float*)d_in[9];
  const float* bo = (const float*)d_in[10];

  short* pat;
  hipGetSymbolAddress((void**)&pat, HIP_SYMBOL(g_at));

  const int nX8 = MROWS*DMODEL/8;     // 524288
  dim3 blk(256);

  cast_all<<<dim3(nX8/256, 1, 7), blk, 0, stream>>>(Q, K, V, Wq, Wk, Wv, Wo);
  proj_qkv<<<dim3(16, 32, 3), blk, 0, stream>>>(bq, bk, bv);
  attn_kernel<<<dim3(SEQ/128, BATCH*NHEAD), dim3(512), 0, stream>>>(pat);
  proj_out<<<dim3(16, 32), blk, 0, stream>>>(bo, (float*)d_out);
}

// Round 15
// 147.360 us; speedup vs baseline: 1.0857x; 1.0857x over previous
//
#include <hip/hip_runtime.h>
#include <hip/hip_bf16.h>

#define DEV __device__ __forceinline__

#define BATCH 2
#define SEQ   2048
#define DMODEL 1024
#define NHEAD 16
#define DK    64
#define MROWS (BATCH*SEQ)   // 4096
#define KD    1024
#define GEMM_NT (KD/32)     // 32 K-iterations

// q-projection scale: (1/sqrt(dk)) * log2(e)  -> scores arrive in exp2 domain
#define QSCALE 0.18033688011112042f

typedef __attribute__((ext_vector_type(4))) float f32x4;
typedef __attribute__((ext_vector_type(8))) short s16x8;
typedef __attribute__((ext_vector_type(4))) float fvec4;
typedef __attribute__((ext_vector_type(2))) unsigned int u32x2;
typedef __attribute__((ext_vector_type(4))) unsigned int u32x4;

// ---------------- scratch (device globals) ---------------------------------
__device__ short g_X[3][MROWS*DMODEL];   // bf16 Q,K,V inputs
__device__ short g_W[4][DMODEL*DMODEL];  // bf16 Wq,Wk,Wv,Wo
__device__ short g_q [MROWS*DMODEL];     // [B,H,S,dk], pre-scaled by QSCALE
__device__ short g_k [MROWS*DMODEL];     // [B,H,S,dk]
__device__ short g_vt[MROWS*DMODEL];     // [B,H,dk,S]
__device__ short g_at[MROWS*DMODEL];     // attention out [B,S,D]

DEV short f2bf(float f) {
  union { __hip_bfloat16 h; short s; } u;
  u.h = __float2bfloat16(f);
  return u.s;
}

// HW RNE pack of two f32 -> two bf16 in one u32 (lo bits 15:0, hi 31:16)
DEV unsigned int f2bf2(float lo, float hi) {
  unsigned int r;
  asm("v_cvt_pk_bf16_f32 %0, %1, %2" : "=v"(r) : "v"(lo), "v"(hi));
  return r;
}

// single-instruction 2^x (avoids OCML multi-inst denormal path; R12-proven)
DEV float fexp2(float x) {
  float r;
  asm("v_exp_f32 %0, %1" : "=v"(r) : "v"(x));
  return r;
}

DEV void gload_lds16(const void* g, void* l) {
  __builtin_amdgcn_global_load_lds(
      (const __attribute__((address_space(1))) void*)g,
      (__attribute__((address_space(3))) void*)l, 16, 0, 0);
}

DEV f32x4 mfma16(s16x8 a, s16x8 b, f32x4 c) {
  return __builtin_amdgcn_mfma_f32_16x16x32_bf16(a, b, c, 0, 0, 0);
}

// ---------------- fused fp32 -> bf16 cast (all 7 tensors, one launch) -------
__global__ __launch_bounds__(256)
void cast_all(const float* __restrict__ q, const float* __restrict__ k,
              const float* __restrict__ v, const float* __restrict__ wq,
              const float* __restrict__ wk, const float* __restrict__ wv,
              const float* __restrict__ wo) {
  int z = blockIdx.z;
  const float* src;
  short* dst;
  int n8;
  if (z < 3) {
    src = z == 0 ? q : z == 1 ? k : v;
    dst = g_X[z];
    n8 = MROWS*DMODEL/8;
  } else {
    src = z == 3 ? wq : z == 4 ? wk : z == 5 ? wv : wo;
    dst = g_W[z - 3];
    n8 = DMODEL*DMODEL/8;
  }
  int i = blockIdx.x * 256 + threadIdx.x;
  if (i < n8) {
    const fvec4* p = (const fvec4*)(src + (size_t)i*8);
    fvec4 v0 = p[0], v1 = p[1];
    u32x4 r;
    r[0] = f2bf2(v0[0], v0[1]); r[1] = f2bf2(v0[2], v0[3]);
    r[2] = f2bf2(v1[0], v1[1]); r[3] = f2bf2(v1[2], v1[3]);
    *(u32x4*)(dst + (size_t)i*8) = r;
  }
}

// ---------------- big-tile GEMM for QKV: 256x256, 8 waves, 3-buf ring -------
// Wave (wm,wn) of 2x4 owns 128x64 output: acc[8][4]. Per K-tile (BK=32):
// 2 phases (N-halves), 16 MFMA each, A-frags read once and reused.
// Stage: 2 half-tiles per phase for tile tau+2 into buf[(tau+2)%3] (slots of
// dead tile tau-1). One counted vmcnt(4) per tile (in-order retirement ->
// tile tau+1's 4 loads retired, tau+2's stay in flight). Never drains.
struct Gemm8Smem { short As[3][256*32]; short Bs[3][256*32]; };  // 96 KB

__global__ __launch_bounds__(512, 2)
void proj_qkv(const float* __restrict__ bq, const float* __restrict__ bk,
              const float* __restrict__ bv) {
  __shared__ Gemm8Smem sm;
  const int t = threadIdx.x, l = t & 63, g = l >> 4, q15 = l & 15;
  const int w = t >> 6, wm = w >> 2, wn = w & 3;
  const int z = blockIdx.z;
  const short* A  = g_X[z];
  const short* Bw = g_W[z];
  const float* bias = z == 0 ? bq : z == 1 ? bk : bv;
  void* outp = z == 0 ? (void*)g_q : z == 1 ? (void*)g_k : (void*)g_vt;
  const float scale = z == 0 ? QSCALE : 1.0f;
  const int mode = z == 2 ? 2 : 1;
  const int rowBase = blockIdx.y * 256;
  const int colBase = blockIdx.x * 256;

  f32x4 acc[8][4] = {};

  // stage half m (rows m*128..+127) of A or B for K-tile tt into buf
  auto stageA = [&](int buf, int tt, int m) {
    int e = m*4096 + t*8;
    int e2 = e ^ (((e >> 7) & 3) << 3);      // pre-swizzled source
    gload_lds16(A + (size_t)(rowBase + (e2 >> 5))*KD + tt*32 + (e2 & 31),
                &sm.As[buf][e]);
  };
  auto stageB = [&](int buf, int tt, int m) {
    int e = m*4096 + t*8;
    int e2 = e ^ (((e >> 7) & 3) << 3);
    gload_lds16(Bw + (size_t)(colBase + (e2 >> 5))*KD + tt*32 + (e2 & 31),
                &sm.Bs[buf][e]);
  };

  // prologue: tiles 0,1 fully staged; vmcnt(4) retires tile 0; barrier
  stageA(0, 0, 0); stageB(0, 0, 0); stageA(0, 0, 1); stageB(0, 0, 1);
  stageA(1, 1, 0); stageB(1, 1, 0); stageA(1, 1, 1); stageB(1, 1, 1);
  asm volatile("s_waitcnt vmcnt(4)" ::: "memory");
  __builtin_amdgcn_s_barrier();
  __builtin_amdgcn_sched_barrier(0);

  int cur = 0, nxt = 2;
  for (int i = 0; i < GEMM_NT; ++i) {
    const int tt2 = (i + 2) & (GEMM_NT - 1);   // wrap tail: junk into dead slots

    // ---- phase 0: A-frags (8) + B-half0 (2); stage A0,B0 of tile i+2 ----
    s16x8 a[8], b[2];
#pragma unroll
    for (int mf = 0; mf < 8; ++mf) {
      int row = wm*128 + mf*16 + q15;
      a[mf] = *(const s16x8*)&sm.As[cur][(row*32 + g*8) ^ (((row >> 2) & 3) << 3)];
    }
#pragma unroll
    for (int nf = 0; nf < 2; ++nf) {
      int row = wn*64 + nf*16 + q15;
      b[nf] = *(const s16x8*)&sm.Bs[cur][(row*32 + g*8) ^ (((row >> 2) & 3) << 3)];
    }
    stageA(nxt, tt2, 0); stageB(nxt, tt2, 0);
    __builtin_amdgcn_s_barrier();
    __builtin_amdgcn_sched_barrier(0);
    __builtin_amdgcn_s_setprio(1);
#pragma unroll
    for (int mf = 0; mf < 8; ++mf)
#pragma unroll
      for (int nf = 0; nf < 2; ++nf)
        acc[mf][nf] = mfma16(a[mf], b[nf], acc[mf][nf]);
    __builtin_amdgcn_s_setprio(0);
    __builtin_amdgcn_s_barrier();
    __builtin_amdgcn_sched_barrier(0);

    // ---- phase 1: B-half1 (2), reuse A-frags; stage A1,B1 of tile i+2 ----
#pragma unroll
    for (int nf = 0; nf < 2; ++nf) {
      int row = wn*64 + (nf + 2)*16 + q15;
      b[nf] = *(const s16x8*)&sm.Bs[cur][(row*32 + g*8) ^ (((row >> 2) & 3) << 3)];
    }
    stageA(nxt, tt2, 1); stageB(nxt, tt2, 1);
    __builtin_amdgcn_s_barrier();
    __builtin_amdgcn_sched_barrier(0);
    __builtin_amdgcn_s_setprio(1);
#pragma unroll
    for (int mf = 0; mf < 8; ++mf)
#pragma unroll
      for (int nf = 0; nf < 2; ++nf)
        acc[mf][nf + 2] = mfma16(a[mf], b[nf], acc[mf][nf + 2]);
    __builtin_amdgcn_s_setprio(0);
    // counted wait: tile i+1's 4 loads retired; tile i+2's 4 stay in flight
    asm volatile("s_waitcnt vmcnt(4)" ::: "memory");
    __builtin_amdgcn_s_barrier();
    __builtin_amdgcn_sched_barrier(0);

    cur = cur == 2 ? 0 : cur + 1;
    nxt = nxt == 2 ? 0 : nxt + 1;
  }
  asm volatile("s_waitcnt vmcnt(0)" ::: "memory");   // drain junk tail stages

  // epilogue: C/D layout col = q15, row = g*4 + r
#pragma unroll
  for (int mf = 0; mf < 8; ++mf) {
    int mrow0 = rowBase + wm*128 + mf*16 + g*4;
#pragma unroll
    for (int nf = 0; nf < 4; ++nf) {
      int n = colBase + wn*64 + nf*16 + q15;
      float bv = bias[n];
      float val[4];
#pragma unroll
      for (int r = 0; r < 4; ++r) val[r] = (acc[mf][nf][r] + bv) * scale;
      unsigned int pk0 = f2bf2(val[0], val[1]);
      unsigned int pk1 = f2bf2(val[2], val[3]);
      int h = n >> 6, d = n & 63;
#pragma unroll
      for (int r = 0; r < 4; ++r) {
        int m = mrow0 + r;
        int b = m >> 11, s = m & 2047;
        unsigned int pk = r < 2 ? pk0 : pk1;
        short sv = (short)((r & 1) ? (pk >> 16) : (pk & 0xffff));
        if (mode == 1)
          ((short*)outp)[(((size_t)(b*NHEAD + h)*SEQ + s)*DK) + d] = sv;
        else
          ((short*)outp)[((size_t)(b*NHEAD + h)*DK + d)*SEQ + s] = sv;
      }
    }
  }
}

// ---------------- 128x128 GEMM core (R13-proven) for the output projection --
struct GemmSmem { short As[2][128*32]; short Bs[2][128*32]; };  // 32 KB

__global__ __launch_bounds__(256, 4)
void proj_out(const float* __restrict__ bo, float* __restrict__ out) {
  __shared__ GemmSmem sm;
  const int t = threadIdx.x, l = t & 63, w = t >> 6, g = l >> 4;
  const int wr = w >> 1, wc = w & 1;
  int orig = blockIdx.y*8 + blockIdx.x;
  int swz = (orig & 7)*32 + (orig >> 3);
  int bx = swz & 7, by = swz >> 3;
  const int rowBase = by*128, colBase = bx*128;
  const short* A = g_at;
  const short* Bw = g_W[3];

  f32x4 acc[4][4] = {};

  auto stage = [&](int buf, int k0) {
#pragma unroll
    for (int j = 0; j < 2; ++j) {
      int e = w*1024 + j*512 + l*8;
      int e2 = e ^ (((e >> 7) & 3) << 3);
      int r = e2 >> 5, c = e2 & 31;
      gload_lds16(A  + (size_t)(rowBase + r)*KD + k0 + c, &sm.As[buf][w*1024 + j*512]);
      gload_lds16(Bw + (size_t)(colBase + r)*KD + k0 + c, &sm.Bs[buf][w*1024 + j*512]);
    }
  };

  stage(0, 0);
  stage(1, 32);

  for (int i = 0; i < GEMM_NT; ++i) {
    if (i < GEMM_NT - 1) asm volatile("s_waitcnt vmcnt(4)" ::: "memory");
    else                 asm volatile("s_waitcnt vmcnt(0)" ::: "memory");
    __builtin_amdgcn_s_barrier();
    __builtin_amdgcn_sched_barrier(0);

    const int cur = i & 1;
    s16x8 a[4], b[4];
#pragma unroll
    for (int x = 0; x < 4; ++x) {
      int ra = wr*64 + x*16 + (l & 15);
      int ia = (ra*32 + g*8) ^ (((ra >> 2) & 3) << 3);
      a[x] = *(const s16x8*)&sm.As[cur][ia];
      int rb = wc*64 + x*16 + (l & 15);
      int ib = (rb*32 + g*8) ^ (((rb >> 2) & 3) << 3);
      b[x] = *(const s16x8*)&sm.Bs[cur][ib];
    }

    __builtin_amdgcn_s_setprio(1);
#pragma unroll
    for (int x = 0; x < 4; ++x)
#pragma unroll
      for (int jn = 0; jn < 4; ++jn)
        acc[x][jn] = mfma16(a[x], b[jn], acc[x][jn]);
    __builtin_amdgcn_s_setprio(0);

    __builtin_amdgcn_s_barrier();
    __builtin_amdgcn_sched_barrier(0);
    if (i + 2 < GEMM_NT) stage(cur, (i + 2)*32);
  }

#pragma unroll
  for (int x = 0; x < 4; ++x) {
    int mrow0 = rowBase + wr*64 + x*16 + g*4;
#pragma unroll
    for (int jn = 0; jn < 4; ++jn) {
      int n = colBase + wc*64 + jn*16 + (l & 15);
      float bv = bo[n];
#pragma unroll
      for (int r = 0; r < 4; ++r)
        out[(size_t)(mrow0 + r)*DMODEL + n] = acc[x][jn][r] + bv;
    }
  }
}

// ---------------- flash attention (unchanged from R12) ----------------------
// split-K: 8 waves, wave w owns q-rows (w&3)*32..+32 over k-tile parity w>>2.
// 4-buffer K/V ring, counted waits, permlane P-rebuild, v_exp_f32 softmax.
__global__ __launch_bounds__(512, 4)
void attn_kernel(short* __restrict__ aout) {
  __shared__ short ks[4][64*64];    // 32 KB (combine: lsum area after loop)
  __shared__ short vs[4][64*64];    // 32 KB (combine: o area after loop)

  const int t = threadIdx.x, l = t & 63, w = t >> 6, g = l >> 4;
  const int q15 = l & 15;
  const int qg = w & 3, kp = w >> 2;
  int orig = blockIdx.y*16 + blockIdx.x;     // 512 blocks, %8==0
  int swz = (orig & 7)*64 + (orig >> 3);     // XCD-chunked, bijective
  const int qblk = swz & 15, bh = swz >> 4;
  const int qbase = qblk * 128;
  const size_t hoff = (size_t)bh * SEQ * DK;

  auto stage_pair = [&](int pr) {
    int e = t*8;                               // 512 thr x 8 shorts = one tile
    int e2 = e ^ (((e >> 6) & 7) << 3);
    int t0 = 2*pr, t1 = t0 + 1;
    gload_lds16(g_k + hoff + (size_t)(t0*64)*DK + e2, &ks[t0 & 3][e]);
    gload_lds16(g_k + hoff + (size_t)(t1*64)*DK + e2, &ks[t1 & 3][e]);
    gload_lds16(g_vt + hoff + (size_t)(e2 >> 6)*SEQ + t0*64 + (e2 & 63), &vs[t0 & 3][e]);
    gload_lds16(g_vt + hoff + (size_t)(e2 >> 6)*SEQ + t1*64 + (e2 & 63), &vs[t1 & 3][e]);
  };

  s16x8 qf[2][2];
  {
    const short* q0 = g_q + hoff + (size_t)(qbase + qg*32 + q15)*DK;
    qf[0][0] = *(const s16x8*)(q0 + g*8);
    qf[0][1] = *(const s16x8*)(q0 + 32 + g*8);
    qf[1][0] = *(const s16x8*)(q0 + 16*DK + g*8);
    qf[1][1] = *(const s16x8*)(q0 + 16*DK + 32 + g*8);
  }
  stage_pair(0);

  float lsum[2] = {0.f, 0.f};
  f32x4 o[2][4] = {};

  for (int i = 0; i < 16; ++i) {
    asm volatile("s_waitcnt vmcnt(0)" ::: "memory");
    __builtin_amdgcn_s_barrier();
    __builtin_amdgcn_sched_barrier(0);
    if (i + 1 < 16) stage_pair(i + 1);   // targets pair i-1's buffers (safe)

    const short* kb = ks[(2*i + kp) & 3];
    const short* vb = vs[(2*i + kp) & 3];

    f32x4 sc[2][4] = {};
    __builtin_amdgcn_s_setprio(1);
#pragma unroll
    for (int ni = 0; ni < 4; ++ni) {
      int row = ni*16 + q15;
      int sx = (row & 7) << 3;
      s16x8 k0 = *(const s16x8*)&kb[(row*64 + g*8) ^ sx];
      s16x8 k1 = *(const s16x8*)&kb[(row*64 + 32 + g*8) ^ sx];
      sc[0][ni] = mfma16(k0, qf[0][0], sc[0][ni]);
      sc[0][ni] = mfma16(k1, qf[0][1], sc[0][ni]);
      sc[1][ni] = mfma16(k0, qf[1][0], sc[1][ni]);
      sc[1][ni] = mfma16(k1, qf[1][1], sc[1][ni]);
    }
    __builtin_amdgcn_s_setprio(0);

    s16x8 pa[2][2];
#pragma unroll
    for (int grp = 0; grp < 2; ++grp) {
      float p[4][4];
#pragma unroll
      for (int ni = 0; ni < 4; ++ni)
#pragma unroll
        for (int r = 0; r < 4; ++r)
          p[ni][r] = fexp2(sc[grp][ni][r]);
      float s0 = (p[0][0]+p[0][1]) + (p[0][2]+p[0][3]);
      float s1 = (p[1][0]+p[1][1]) + (p[1][2]+p[1][3]);
      float s2 = (p[2][0]+p[2][1]) + (p[2][2]+p[2][3]);
      float s3 = (p[3][0]+p[3][1]) + (p[3][2]+p[3][3]);
      lsum[grp] += (s0+s1) + (s2+s3);

      unsigned pk[4][2];
#pragma unroll
      for (int ni = 0; ni < 4; ++ni) {
        pk[ni][0] = f2bf2(p[ni][0], p[ni][1]);
        pk[ni][1] = f2bf2(p[ni][2], p[ni][3]);
      }
#pragma unroll
      for (int kf = 0; kf < 2; ++kf) {
        u32x4 P4;
#pragma unroll
        for (int u = 0; u < 2; ++u) {
          unsigned x = pk[2*kf][u], y = pk[2*kf + 1][u];
          asm("v_permlane32_swap_b32 %0, %1" : "+v"(x), "+v"(y));
          asm("v_permlane16_swap_b32 %0, %1" : "+v"(x), "+v"(y));
          P4[u]     = x;
          P4[2 + u] = y;
        }
        union { u32x4 u4; s16x8 s8; } cv;
        cv.u4 = P4;
        pa[grp][kf] = cv.s8;
      }
    }

    __builtin_amdgcn_s_setprio(1);
#pragma unroll
    for (int nd = 0; nd < 4; ++nd) {
      int row = nd*16 + q15;
      int sx = (row & 7) << 3;
      s16x8 v0 = *(const s16x8*)&vb[(row*64 + g*8) ^ sx];
      s16x8 v1 = *(const s16x8*)&vb[(row*64 + 32 + g*8) ^ sx];
      o[0][nd] = mfma16(pa[0][0], v0, o[0][nd]);
      o[0][nd] = mfma16(pa[0][1], v1, o[0][nd]);
      o[1][nd] = mfma16(pa[1][0], v0, o[1][nd]);
      o[1][nd] = mfma16(pa[1][1], v1, o[1][nd]);
    }
    __builtin_amdgcn_s_setprio(0);
  }

  // ---- split-K combine ----
  __syncthreads();
  float* ob = (float*)&vs[0][0];
  float* lb = (float*)&ks[0][0];
  if (kp) {
#pragma unroll
    for (int grp = 0; grp < 2; ++grp) {
#pragma unroll
      for (int nd = 0; nd < 4; ++nd)
#pragma unroll
        for (int r = 0; r < 4; ++r)
          ob[(qg*32 + grp*16 + nd*4 + r)*64 + l] = o[grp][nd][r];
      lb[(qg*2 + grp)*64 + l] = lsum[grp];
    }
  }
  __syncthreads();
  if (!kp) {
    int b = bh >> 4, h = bh & 15;
#pragma unroll
    for (int grp = 0; grp < 2; ++grp) {
#pragma unroll
      for (int nd = 0; nd < 4; ++nd)
#pragma unroll
        for (int r = 0; r < 4; ++r)
          o[grp][nd][r] += ob[(qg*32 + grp*16 + nd*4 + r)*64 + l];
      float ls = lsum[grp] + lb[(qg*2 + grp)*64 + l];
      ls += __shfl_xor(ls, 16);
      ls += __shfl_xor(ls, 32);
      float inv = 1.0f / ls;
      float iv[4];
#pragma unroll
      for (int r = 0; r < 4; ++r)
        iv[r] = __shfl(inv, (l & 48) | (g*4 + r));
#pragma unroll
      for (int nd = 0; nd < 4; ++nd) {
        int dcol = h*DK + nd*16 + q15;
#pragma unroll
        for (int r = 0; r < 4; ++r) {
          int srow = qbase + qg*32 + grp*16 + g*4 + r;
          aout[((size_t)(b*SEQ + srow))*DMODEL + dcol] = f2bf(o[grp][nd][r] * iv[r]);
        }
      }
    }
  }
}

// ---------------- host side -------------------------------------------------
extern "C" void kernel_launch(void* const* d_in, const int* in_sizes, int n_in,
                              void* d_out, int out_size, void* d_ws, size_t ws_size,
                              hipStream_t stream) {
  const float* Q  = (const float*)d_in[0];
  const float* K  = (const float*)d_in[1];
  const float* V  = (const float*)d_in[2];
  const float* Wq = (const float*)d_in[3];
  const float* bq = (const float*)d_in[4];
  const float* Wk = (const float*)d_in[5];
  const float* bk = (const float*)d_in[6];
  const float* Wv = (const float*)d_in[7];
  const float* bv = (const float*)d_in[8];
  const float* Wo = (const float*)d_in[9];
  const float* bo = (const float*)d_in[10];

  short* pat;
  hipGetSymbolAddress((void**)&pat, HIP_SYMBOL(g_at));

  const int nX8 = MROWS*DMODEL/8;     // 524288
  dim3 blk(256);

  cast_all<<<dim3(nX8/256, 1, 7), blk, 0, stream>>>(Q, K, V, Wq, Wk, Wv, Wo);
  proj_qkv<<<dim3(4, 16, 3), dim3(512), 0, stream>>>(bq, bk, bv);
  attn_kernel<<<dim3(SEQ/128, BATCH*NHEAD), dim3(512), 0, stream>>>(pat);
  proj_out<<<dim3(8, 32), blk, 0, stream>>>(bo, (float*)d_out);
}

// Round 16
// 143.245 us; speedup vs baseline: 1.1169x; 1.0287x over previous
//
#include <hip/hip_runtime.h>
#include <hip/hip_bf16.h>

#define DEV __device__ __forceinline__

#define BATCH 2
#define SEQ   2048
#define DMODEL 1024
#define NHEAD 16
#define DK    64
#define MROWS (BATCH*SEQ)   // 4096
#define KD    1024
#define GEMM_NT (KD/32)     // 32 K-iterations

// q-projection scale: (1/sqrt(dk)) * log2(e)  -> scores arrive in exp2 domain
#define QSCALE 0.18033688011112042f

typedef __attribute__((ext_vector_type(4))) float f32x4;
typedef __attribute__((ext_vector_type(8))) short s16x8;
typedef __attribute__((ext_vector_type(4))) float fvec4;
typedef __attribute__((ext_vector_type(2))) unsigned int u32x2;
typedef __attribute__((ext_vector_type(4))) unsigned int u32x4;

// ---------------- scratch (device globals) ---------------------------------
__device__ short g_X[3][MROWS*DMODEL];   // bf16 Q,K,V inputs
__device__ short g_W[4][DMODEL*DMODEL];  // bf16 Wq,Wk,Wv,Wo
__device__ short g_q [MROWS*DMODEL];     // [B,H,S,dk], pre-scaled by QSCALE
__device__ short g_k [MROWS*DMODEL];     // [B,H,S,dk]
__device__ short g_vt[MROWS*DMODEL];     // [B,H,dk,S]
__device__ short g_at[MROWS*DMODEL];     // attention out [B,S,D]

DEV short f2bf(float f) {
  union { __hip_bfloat16 h; short s; } u;
  u.h = __float2bfloat16(f);
  return u.s;
}

// HW RNE pack of two f32 -> two bf16 in one u32 (lo bits 15:0, hi 31:16)
DEV unsigned int f2bf2(float lo, float hi) {
  unsigned int r;
  asm("v_cvt_pk_bf16_f32 %0, %1, %2" : "=v"(r) : "v"(lo), "v"(hi));
  return r;
}

// single-instruction 2^x (avoids OCML multi-inst denormal path; R12-proven)
DEV float fexp2(float x) {
  float r;
  asm("v_exp_f32 %0, %1" : "=v"(r) : "v"(x));
  return r;
}

DEV void gload_lds16(const void* g, void* l) {
  __builtin_amdgcn_global_load_lds(
      (const __attribute__((address_space(1))) void*)g,
      (__attribute__((address_space(3))) void*)l, 16, 0, 0);
}

DEV f32x4 mfma16(s16x8 a, s16x8 b, f32x4 c) {
  return __builtin_amdgcn_mfma_f32_16x16x32_bf16(a, b, c, 0, 0, 0);
}

// ---------------- fused fp32 -> bf16 cast (all 7 tensors, one launch) -------
__global__ __launch_bounds__(256)
void cast_all(const float* __restrict__ q, const float* __restrict__ k,
              const float* __restrict__ v, const float* __restrict__ wq,
              const float* __restrict__ wk, const float* __restrict__ wv,
              const float* __restrict__ wo) {
  int z = blockIdx.z;
  const float* src;
  short* dst;
  int n8;
  if (z < 3) {
    src = z == 0 ? q : z == 1 ? k : v;
    dst = g_X[z];
    n8 = MROWS*DMODEL/8;
  } else {
    src = z == 3 ? wq : z == 4 ? wk : z == 5 ? wv : wo;
    dst = g_W[z - 3];
    n8 = DMODEL*DMODEL/8;
  }
  int i = blockIdx.x * 256 + threadIdx.x;
  if (i < n8) {
    const fvec4* p = (const fvec4*)(src + (size_t)i*8);
    fvec4 v0 = p[0], v1 = p[1];
    u32x4 r;
    r[0] = f2bf2(v0[0], v0[1]); r[1] = f2bf2(v0[2], v0[3]);
    r[2] = f2bf2(v1[0], v1[1]); r[3] = f2bf2(v1[2], v1[3]);
    *(u32x4*)(dst + (size_t)i*8) = r;
  }
}

// ---------------- unified 128x128 GEMM (R12-proven 3-buffer core) -----------
// One GEMM per dispatch (grid 8x32 = 256 blocks = 1/CU, like proj_out which
// measured ~573 TF vs 437 TF for the z-fused 3/CU variant). Counted vmcnt(4),
// one barrier per iter, swizzled LDS.
struct GemmSmem { short As[3][128*32]; short Bs[3][128*32]; };  // 48 KB

__global__ __launch_bounds__(256, 3)
void proj_gemm(const short* __restrict__ A, const short* __restrict__ Bw,
               const float* __restrict__ bias, void* __restrict__ outp,
               float scale, int mode) {
  __shared__ GemmSmem sm;
  const int t = threadIdx.x, l = t & 63, w = t >> 6, g = l >> 4;
  const int wr = w >> 1, wc = w & 1;
  int orig = blockIdx.y*8 + blockIdx.x;
  int swz = (orig & 7)*32 + (orig >> 3);     // XCD-chunked, bijective
  const int rowBase = (swz >> 3)*128, colBase = (swz & 7)*128;

  f32x4 acc[4][4] = {};

  auto stage = [&](int buf, int k0) {
#pragma unroll
    for (int j = 0; j < 2; ++j) {
      int e = w*1024 + j*512 + l*8;
      int e2 = e ^ (((e >> 7) & 3) << 3);
      int r = e2 >> 5, c = e2 & 31;
      gload_lds16(A  + (size_t)(rowBase + r)*KD + k0 + c, &sm.As[buf][w*1024 + j*512]);
      gload_lds16(Bw + (size_t)(colBase + r)*KD + k0 + c, &sm.Bs[buf][w*1024 + j*512]);
    }
  };

  stage(0, 0);
  stage(1, 32);

  int cur = 0, nxt = 2;
  for (int i = 0; i < GEMM_NT; ++i) {
    if (i < GEMM_NT - 1) asm volatile("s_waitcnt vmcnt(4)" ::: "memory");
    else                 asm volatile("s_waitcnt vmcnt(0)" ::: "memory");
    __builtin_amdgcn_s_barrier();
    __builtin_amdgcn_sched_barrier(0);

    s16x8 a[4], b[4];
#pragma unroll
    for (int x = 0; x < 4; ++x) {
      int ra = wr*64 + x*16 + (l & 15);
      int ia = (ra*32 + g*8) ^ (((ra >> 2) & 3) << 3);
      a[x] = *(const s16x8*)&sm.As[cur][ia];
      int rb = wc*64 + x*16 + (l & 15);
      int ib = (rb*32 + g*8) ^ (((rb >> 2) & 3) << 3);
      b[x] = *(const s16x8*)&sm.Bs[cur][ib];
    }
    if (i + 2 < GEMM_NT) stage(nxt, (i + 2)*32);
    __builtin_amdgcn_sched_barrier(0);

    __builtin_amdgcn_s_setprio(1);
#pragma unroll
    for (int x = 0; x < 4; ++x)
#pragma unroll
      for (int jn = 0; jn < 4; ++jn)
        acc[x][jn] = mfma16(a[x], b[jn], acc[x][jn]);
    __builtin_amdgcn_s_setprio(0);

    cur = cur == 2 ? 0 : cur + 1;
    nxt = nxt == 2 ? 0 : nxt + 1;
  }

#pragma unroll
  for (int x = 0; x < 4; ++x) {
    int mrow0 = rowBase + wr*64 + x*16 + g*4;
#pragma unroll
    for (int jn = 0; jn < 4; ++jn) {
      int n = colBase + wc*64 + jn*16 + (l & 15);
      float bv = bias[n];
      float val[4];
#pragma unroll
      for (int r = 0; r < 4; ++r) val[r] = (acc[x][jn][r] + bv) * scale;
      if (mode == 3) {
#pragma unroll
        for (int r = 0; r < 4; ++r)
          ((float*)outp)[(size_t)(mrow0 + r)*DMODEL + n] = val[r];
      } else {
        unsigned int pk0 = f2bf2(val[0], val[1]);
        unsigned int pk1 = f2bf2(val[2], val[3]);
        int h = n >> 6, d = n & 63;
#pragma unroll
        for (int r = 0; r < 4; ++r) {
          int m = mrow0 + r;
          int b = m >> 11, s = m & 2047;
          unsigned int pk = r < 2 ? pk0 : pk1;
          short sv = (short)((r & 1) ? (pk >> 16) : (pk & 0xffff));
          if (mode == 1)
            ((short*)outp)[(((size_t)(b*NHEAD + h)*SEQ + s)*DK) + d] = sv;
          else
            ((short*)outp)[((size_t)(b*NHEAD + h)*DK + d)*SEQ + s] = sv;
        }
      }
    }
  }
}

// ---------------- flash attention (unchanged from R12) ----------------------
// split-K: 8 waves, wave w owns q-rows (w&3)*32..+32 over k-tile parity w>>2.
// 4-buffer K/V ring, counted waits, permlane P-rebuild, v_exp_f32 softmax.
__global__ __launch_bounds__(512, 4)
void attn_kernel(short* __restrict__ aout) {
  __shared__ short ks[4][64*64];    // 32 KB (combine: lsum area after loop)
  __shared__ short vs[4][64*64];    // 32 KB (combine: o area after loop)

  const int t = threadIdx.x, l = t & 63, w = t >> 6, g = l >> 4;
  const int q15 = l & 15;
  const int qg = w & 3, kp = w >> 2;
  int orig = blockIdx.y*16 + blockIdx.x;     // 512 blocks, %8==0
  int swz = (orig & 7)*64 + (orig >> 3);     // XCD-chunked, bijective
  const int qblk = swz & 15, bh = swz >> 4;
  const int qbase = qblk * 128;
  const size_t hoff = (size_t)bh * SEQ * DK;

  auto stage_pair = [&](int pr) {
    int e = t*8;                               // 512 thr x 8 shorts = one tile
    int e2 = e ^ (((e >> 6) & 7) << 3);
    int t0 = 2*pr, t1 = t0 + 1;
    gload_lds16(g_k + hoff + (size_t)(t0*64)*DK + e2, &ks[t0 & 3][e]);
    gload_lds16(g_k + hoff + (size_t)(t1*64)*DK + e2, &ks[t1 & 3][e]);
    gload_lds16(g_vt + hoff + (size_t)(e2 >> 6)*SEQ + t0*64 + (e2 & 63), &vs[t0 & 3][e]);
    gload_lds16(g_vt + hoff + (size_t)(e2 >> 6)*SEQ + t1*64 + (e2 & 63), &vs[t1 & 3][e]);
  };

  s16x8 qf[2][2];
  {
    const short* q0 = g_q + hoff + (size_t)(qbase + qg*32 + q15)*DK;
    qf[0][0] = *(const s16x8*)(q0 + g*8);
    qf[0][1] = *(const s16x8*)(q0 + 32 + g*8);
    qf[1][0] = *(const s16x8*)(q0 + 16*DK + g*8);
    qf[1][1] = *(const s16x8*)(q0 + 16*DK + 32 + g*8);
  }
  stage_pair(0);

  float lsum[2] = {0.f, 0.f};
  f32x4 o[2][4] = {};

  for (int i = 0; i < 16; ++i) {
    asm volatile("s_waitcnt vmcnt(0)" ::: "memory");
    __builtin_amdgcn_s_barrier();
    __builtin_amdgcn_sched_barrier(0);
    if (i + 1 < 16) stage_pair(i + 1);   // targets pair i-1's buffers (safe)

    const short* kb = ks[(2*i + kp) & 3];
    const short* vb = vs[(2*i + kp) & 3];

    f32x4 sc[2][4] = {};
    __builtin_amdgcn_s_setprio(1);
#pragma unroll
    for (int ni = 0; ni < 4; ++ni) {
      int row = ni*16 + q15;
      int sx = (row & 7) << 3;
      s16x8 k0 = *(const s16x8*)&kb[(row*64 + g*8) ^ sx];
      s16x8 k1 = *(const s16x8*)&kb[(row*64 + 32 + g*8) ^ sx];
      sc[0][ni] = mfma16(k0, qf[0][0], sc[0][ni]);
      sc[0][ni] = mfma16(k1, qf[0][1], sc[0][ni]);
      sc[1][ni] = mfma16(k0, qf[1][0], sc[1][ni]);
      sc[1][ni] = mfma16(k1, qf[1][1], sc[1][ni]);
    }
    __builtin_amdgcn_s_setprio(0);

    s16x8 pa[2][2];
#pragma unroll
    for (int grp = 0; grp < 2; ++grp) {
      float p[4][4];
#pragma unroll
      for (int ni = 0; ni < 4; ++ni)
#pragma unroll
        for (int r = 0; r < 4; ++r)
          p[ni][r] = fexp2(sc[grp][ni][r]);
      float s0 = (p[0][0]+p[0][1]) + (p[0][2]+p[0][3]);
      float s1 = (p[1][0]+p[1][1]) + (p[1][2]+p[1][3]);
      float s2 = (p[2][0]+p[2][1]) + (p[2][2]+p[2][3]);
      float s3 = (p[3][0]+p[3][1]) + (p[3][2]+p[3][3]);
      lsum[grp] += (s0+s1) + (s2+s3);

      unsigned pk[4][2];
#pragma unroll
      for (int ni = 0; ni < 4; ++ni) {
        pk[ni][0] = f2bf2(p[ni][0], p[ni][1]);
        pk[ni][1] = f2bf2(p[ni][2], p[ni][3]);
      }
#pragma unroll
      for (int kf = 0; kf < 2; ++kf) {
        u32x4 P4;
#pragma unroll
        for (int u = 0; u < 2; ++u) {
          unsigned x = pk[2*kf][u], y = pk[2*kf + 1][u];
          asm("v_permlane32_swap_b32 %0, %1" : "+v"(x), "+v"(y));
          asm("v_permlane16_swap_b32 %0, %1" : "+v"(x), "+v"(y));
          P4[u]     = x;
          P4[2 + u] = y;
        }
        union { u32x4 u4; s16x8 s8; } cv;
        cv.u4 = P4;
        pa[grp][kf] = cv.s8;
      }
    }

    __builtin_amdgcn_s_setprio(1);
#pragma unroll
    for (int nd = 0; nd < 4; ++nd) {
      int row = nd*16 + q15;
      int sx = (row & 7) << 3;
      s16x8 v0 = *(const s16x8*)&vb[(row*64 + g*8) ^ sx];
      s16x8 v1 = *(const s16x8*)&vb[(row*64 + 32 + g*8) ^ sx];
      o[0][nd] = mfma16(pa[0][0], v0, o[0][nd]);
      o[0][nd] = mfma16(pa[0][1], v1, o[0][nd]);
      o[1][nd] = mfma16(pa[1][0], v0, o[1][nd]);
      o[1][nd] = mfma16(pa[1][1], v1, o[1][nd]);
    }
    __builtin_amdgcn_s_setprio(0);
  }

  // ---- split-K combine ----
  __syncthreads();
  float* ob = (float*)&vs[0][0];
  float* lb = (float*)&ks[0][0];
  if (kp) {
#pragma unroll
    for (int grp = 0; grp < 2; ++grp) {
#pragma unroll
      for (int nd = 0; nd < 4; ++nd)
#pragma unroll
        for (int r = 0; r < 4; ++r)
          ob[(qg*32 + grp*16 + nd*4 + r)*64 + l] = o[grp][nd][r];
      lb[(qg*2 + grp)*64 + l] = lsum[grp];
    }
  }
  __syncthreads();
  if (!kp) {
    int b = bh >> 4, h = bh & 15;
#pragma unroll
    for (int grp = 0; grp < 2; ++grp) {
#pragma unroll
      for (int nd = 0; nd < 4; ++nd)
#pragma unroll
        for (int r = 0; r < 4; ++r)
          o[grp][nd][r] += ob[(qg*32 + grp*16 + nd*4 + r)*64 + l];
      float ls = lsum[grp] + lb[(qg*2 + grp)*64 + l];
      ls += __shfl_xor(ls, 16);
      ls += __shfl_xor(ls, 32);
      float inv = 1.0f / ls;
      float iv[4];
#pragma unroll
      for (int r = 0; r < 4; ++r)
        iv[r] = __shfl(inv, (l & 48) | (g*4 + r));
#pragma unroll
      for (int nd = 0; nd < 4; ++nd) {
        int dcol = h*DK + nd*16 + q15;
#pragma unroll
        for (int r = 0; r < 4; ++r) {
          int srow = qbase + qg*32 + grp*16 + g*4 + r;
          aout[((size_t)(b*SEQ + srow))*DMODEL + dcol] = f2bf(o[grp][nd][r] * iv[r]);
        }
      }
    }
  }
}

// ---------------- host side -------------------------------------------------
extern "C" void kernel_launch(void* const* d_in, const int* in_sizes, int n_in,
                              void* d_out, int out_size, void* d_ws, size_t ws_size,
                              hipStream_t stream) {
  const float* Q  = (const float*)d_in[0];
  const float* K  = (const float*)d_in[1];
  const float* V  = (const float*)d_in[2];
  const float* Wq = (const float*)d_in[3];
  const float* bq = (const float*)d_in[4];
  const float* Wk = (const float*)d_in[5];
  const float* bk = (const float*)d_in[6];
  const float* Wv = (const float*)d_in[7];
  const float* bv = (const float*)d_in[8];
  const float* Wo = (const float*)d_in[9];
  const float* bo = (const float*)d_in[10];

  short *pX, *pW, *pq, *pk, *pvt, *pat;
  hipGetSymbolAddress((void**)&pX,  HIP_SYMBOL(g_X));
  hipGetSymbolAddress((void**)&pW,  HIP_SYMBOL(g_W));
  hipGetSymbolAddress((void**)&pq,  HIP_SYMBOL(g_q));
  hipGetSymbolAddress((void**)&pk,  HIP_SYMBOL(g_k));
  hipGetSymbolAddress((void**)&pvt, HIP_SYMBOL(g_vt));
  hipGetSymbolAddress((void**)&pat, HIP_SYMBOL(g_at));

  const int nX8 = MROWS*DMODEL/8;     // 524288
  const size_t NX = (size_t)MROWS*DMODEL;
  const size_t NW = (size_t)DMODEL*DMODEL;
  dim3 blk(256);
  dim3 gP(8, 32);

  cast_all<<<dim3(nX8/256, 1, 7), blk, 0, stream>>>(Q, K, V, Wq, Wk, Wv, Wo);
  proj_gemm<<<gP, blk, 0, stream>>>(pX,        pW,        bq, pq,  QSCALE, 1);
  proj_gemm<<<gP, blk, 0, stream>>>(pX + NX,   pW + NW,   bk, pk,  1.0f,   1);
  proj_gemm<<<gP, blk, 0, stream>>>(pX + 2*NX, pW + 2*NW, bv, pvt, 1.0f,   2);
  attn_kernel<<<dim3(SEQ/128, BATCH*NHEAD), dim3(512), 0, stream>>>(pat);
  proj_gemm<<<gP, blk, 0, stream>>>(pat, pW + 3*NW, bo, (float*)d_out, 1.0f, 3);
}

// Round 17
// 128.430 us; speedup vs baseline: 1.2457x; 1.1154x over previous
//
#include <hip/hip_runtime.h>
#include <hip/hip_bf16.h>

#define DEV __device__ __forceinline__

#define BATCH 2
#define SEQ   2048
#define DMODEL 1024
#define NHEAD 16
#define DK    64
#define MROWS (BATCH*SEQ)   // 4096
#define KD    1024
#define GEMM_NT (KD/32)     // 32 K-iterations

// q-projection scale: (1/sqrt(dk)) * log2(e)  -> scores arrive in exp2 domain
#define QSCALE 0.18033688011112042f

typedef __attribute__((ext_vector_type(4))) float f32x4;
typedef __attribute__((ext_vector_type(8))) short s16x8;
typedef __attribute__((ext_vector_type(4))) float fvec4;
typedef __attribute__((ext_vector_type(2))) unsigned int u32x2;
typedef __attribute__((ext_vector_type(4))) unsigned int u32x4;

// ---------------- scratch (device globals) ---------------------------------
__device__ short g_X[3][MROWS*DMODEL];   // bf16 Q,K,V inputs
__device__ short g_W[4][DMODEL*DMODEL];  // bf16 Wq,Wk,Wv,Wo
__device__ short g_q [MROWS*DMODEL];     // [B,H,S,dk], pre-scaled by QSCALE
__device__ short g_k [MROWS*DMODEL];     // [B,H,S,dk]
__device__ short g_vt[MROWS*DMODEL];     // [B,H,dk,S]
__device__ short g_at[MROWS*DMODEL];     // attention out [B,S,D]

DEV short f2bf(float f) {
  union { __hip_bfloat16 h; short s; } u;
  u.h = __float2bfloat16(f);
  return u.s;
}

// HW RNE pack of two f32 -> two bf16 in one u32 (lo bits 15:0, hi 31:16)
DEV unsigned int f2bf2(float lo, float hi) {
  unsigned int r;
  asm("v_cvt_pk_bf16_f32 %0, %1, %2" : "=v"(r) : "v"(lo), "v"(hi));
  return r;
}

// single-instruction 2^x (avoids OCML multi-inst denormal path; R12-proven)
DEV float fexp2(float x) {
  float r;
  asm("v_exp_f32 %0, %1" : "=v"(r) : "v"(x));
  return r;
}

DEV void gload_lds16(const void* g, void* l) {
  __builtin_amdgcn_global_load_lds(
      (const __attribute__((address_space(1))) void*)g,
      (__attribute__((address_space(3))) void*)l, 16, 0, 0);
}

DEV f32x4 mfma16(s16x8 a, s16x8 b, f32x4 c) {
  return __builtin_amdgcn_mfma_f32_16x16x32_bf16(a, b, c, 0, 0, 0);
}

// ---------------- fused fp32 -> bf16 cast (all 7 tensors, one launch) -------
__global__ __launch_bounds__(256)
void cast_all(const float* __restrict__ q, const float* __restrict__ k,
              const float* __restrict__ v, const float* __restrict__ wq,
              const float* __restrict__ wk, const float* __restrict__ wv,
              const float* __restrict__ wo) {
  int z = blockIdx.z;
  const float* src;
  short* dst;
  int n8;
  if (z < 3) {
    src = z == 0 ? q : z == 1 ? k : v;
    dst = g_X[z];
    n8 = MROWS*DMODEL/8;
  } else {
    src = z == 3 ? wq : z == 4 ? wk : z == 5 ? wv : wo;
    dst = g_W[z - 3];
    n8 = DMODEL*DMODEL/8;
  }
  int i = blockIdx.x * 256 + threadIdx.x;
  if (i < n8) {
    const fvec4* p = (const fvec4*)(src + (size_t)i*8);
    fvec4 v0 = p[0], v1 = p[1];
    u32x4 r;
    r[0] = f2bf2(v0[0], v0[1]); r[1] = f2bf2(v0[2], v0[3]);
    r[2] = f2bf2(v1[0], v1[1]); r[3] = f2bf2(v1[2], v1[3]);
    *(u32x4*)(dst + (size_t)i*8) = r;
  }
}

// ---------------- 128x128 GEMM core (R12-proven 3-buffer) -------------------
// Counted vmcnt(4), one barrier/iter, swizzled LDS staging. Mode-2 (V^T)
// epilogue round-trips C through the dead staging LDS to turn 4KB-stride
// 2B scattered stores into contiguous 128B global_store_dwordx4 runs.
struct GemmSmem { short As[3][128*32]; short Bs[3][128*32]; };  // 48 KB

DEV void gemm_core(GemmSmem& sm, const short* __restrict__ A,
                   const short* __restrict__ Bw, const float* __restrict__ bias,
                   void* __restrict__ outp, float scale, int mode,
                   int rowBase, int colBase) {
  const int t = threadIdx.x, l = t & 63, w = t >> 6, g = l >> 4;
  const int q15 = l & 15;
  const int wr = w >> 1, wc = w & 1;

  f32x4 acc[4][4] = {};

  auto stage = [&](int buf, int k0) {
#pragma unroll
    for (int j = 0; j < 2; ++j) {
      int e = w*1024 + j*512 + l*8;
      int e2 = e ^ (((e >> 7) & 3) << 3);
      int r = e2 >> 5, c = e2 & 31;
      gload_lds16(A  + (size_t)(rowBase + r)*KD + k0 + c, &sm.As[buf][w*1024 + j*512]);
      gload_lds16(Bw + (size_t)(colBase + r)*KD + k0 + c, &sm.Bs[buf][w*1024 + j*512]);
    }
  };

  stage(0, 0);
  stage(1, 32);

  int cur = 0, nxt = 2;
  for (int i = 0; i < GEMM_NT; ++i) {
    if (i < GEMM_NT - 1) asm volatile("s_waitcnt vmcnt(4)" ::: "memory");
    else                 asm volatile("s_waitcnt vmcnt(0)" ::: "memory");
    __builtin_amdgcn_s_barrier();
    __builtin_amdgcn_sched_barrier(0);

    s16x8 a[4], b[4];
#pragma unroll
    for (int x = 0; x < 4; ++x) {
      int ra = wr*64 + x*16 + q15;
      int ia = (ra*32 + g*8) ^ (((ra >> 2) & 3) << 3);
      a[x] = *(const s16x8*)&sm.As[cur][ia];
      int rb = wc*64 + x*16 + q15;
      int ib = (rb*32 + g*8) ^ (((rb >> 2) & 3) << 3);
      b[x] = *(const s16x8*)&sm.Bs[cur][ib];
    }
    if (i + 2 < GEMM_NT) stage(nxt, (i + 2)*32);
    __builtin_amdgcn_sched_barrier(0);

    __builtin_amdgcn_s_setprio(1);
#pragma unroll
    for (int x = 0; x < 4; ++x)
#pragma unroll
      for (int jn = 0; jn < 4; ++jn)
        acc[x][jn] = mfma16(a[x], b[jn], acc[x][jn]);
    __builtin_amdgcn_s_setprio(0);

    cur = cur == 2 ? 0 : cur + 1;
    nxt = nxt == 2 ? 0 : nxt + 1;
  }

  if (mode == 2) {
    // ---- V^T epilogue via LDS transpose (coalesced stores) ----
    short* ct = (short*)&sm;           // 32 KB [n=128][m=128], XOR-swizzled
    __syncthreads();                   // all waves done with staging LDS
#pragma unroll
    for (int x = 0; x < 4; ++x) {
      int m0 = wr*64 + x*16 + g*4;
#pragma unroll
      for (int jn = 0; jn < 4; ++jn) {
        int n = wc*64 + jn*16 + q15;
        float bv = bias[colBase + n];
        u32x2 w2;
        w2[0] = f2bf2(acc[x][jn][0] + bv, acc[x][jn][1] + bv);
        w2[1] = f2bf2(acc[x][jn][2] + bv, acc[x][jn][3] + bv);
        int mi = m0 ^ ((n & 15) << 3);
        *(u32x2*)&ct[n*128 + mi] = w2;
      }
    }
    __syncthreads();
    // thread t: row n = t>>1 (global col = d of head h), half c = t&1
    int c = t & 1, n = t >> 1;
    int ng = colBase + n;
    int h = ng >> 6, d = ng & 63;
    int b = rowBase >> 11;
    int s0 = (rowBase & 2047) + c*64;
    short* dst = (short*)outp + ((size_t)(b*NHEAD + h)*DK + d)*SEQ + s0;
#pragma unroll
    for (int j = 0; j < 8; ++j) {
      int mi = (c*64 + j*8) ^ ((n & 15) << 3);
      *(s16x8*)&dst[j*8] = *(const s16x8*)&ct[n*128 + mi];
    }
    return;
  }

#pragma unroll
  for (int x = 0; x < 4; ++x) {
    int mrow0 = rowBase + wr*64 + x*16 + g*4;
#pragma unroll
    for (int jn = 0; jn < 4; ++jn) {
      int n = colBase + wc*64 + jn*16 + q15;
      float bv = bias[n];
      float val[4];
#pragma unroll
      for (int r = 0; r < 4; ++r) val[r] = (acc[x][jn][r] + bv) * scale;
      if (mode == 3) {
#pragma unroll
        for (int r = 0; r < 4; ++r)
          ((float*)outp)[(size_t)(mrow0 + r)*DMODEL + n] = val[r];
      } else {
        unsigned int pk0 = f2bf2(val[0], val[1]);
        unsigned int pk1 = f2bf2(val[2], val[3]);
        int h = n >> 6, d = n & 63;
#pragma unroll
        for (int r = 0; r < 4; ++r) {
          int m = mrow0 + r;
          int b = m >> 11, s = m & 2047;
          unsigned int pk = r < 2 ? pk0 : pk1;
          short sv = (short)((r & 1) ? (pk >> 16) : (pk & 0xffff));
          ((short*)outp)[(((size_t)(b*NHEAD + h)*SEQ + s)*DK) + d] = sv;
        }
      }
    }
  }
}

// fused Q/K/V projections: grid (8, 32, 3) -> 768 blocks = 3/CU (R12-proven)
__global__ __launch_bounds__(256, 3)
void proj_qkv(const float* __restrict__ bq, const float* __restrict__ bk,
              const float* __restrict__ bv) {
  __shared__ GemmSmem sm;
  int z = blockIdx.z;
  int orig = blockIdx.y*8 + blockIdx.x;
  int swz = (orig & 7)*32 + (orig >> 3);
  int bx = swz & 7, by = swz >> 3;
  const float* bias = z == 0 ? bq : z == 1 ? bk : bv;
  void* outp = z == 0 ? (void*)g_q : z == 1 ? (void*)g_k : (void*)g_vt;
  gemm_core(sm, g_X[z], g_W[z], bias, outp, z == 0 ? QSCALE : 1.0f,
            z == 2 ? 2 : 1, by*128, bx*128);
}

__global__ __launch_bounds__(256, 3)
void proj_out(const float* __restrict__ bo, float* __restrict__ out) {
  __shared__ GemmSmem sm;
  int orig = blockIdx.y*8 + blockIdx.x;
  int swz = (orig & 7)*32 + (orig >> 3);
  int bx = swz & 7, by = swz >> 3;
  gemm_core(sm, g_at, g_W[3], bo, out, 1.0f, 3, by*128, bx*128);
}

// ---------------- flash attention (unchanged from R12/R16) ------------------
// split-K: 8 waves, wave w owns q-rows (w&3)*32..+32 over k-tile parity w>>2.
// 4-buffer K/V ring, counted waits, permlane P-rebuild, v_exp_f32 softmax.
__global__ __launch_bounds__(512, 4)
void attn_kernel(short* __restrict__ aout) {
  __shared__ short ks[4][64*64];    // 32 KB (combine: lsum area after loop)
  __shared__ short vs[4][64*64];    // 32 KB (combine: o area after loop)

  const int t = threadIdx.x, l = t & 63, w = t >> 6, g = l >> 4;
  const int q15 = l & 15;
  const int qg = w & 3, kp = w >> 2;
  int orig = blockIdx.y*16 + blockIdx.x;     // 512 blocks, %8==0
  int swz = (orig & 7)*64 + (orig >> 3);     // XCD-chunked, bijective
  const int qblk = swz & 15, bh = swz >> 4;
  const int qbase = qblk * 128;
  const size_t hoff = (size_t)bh * SEQ * DK;

  auto stage_pair = [&](int pr) {
    int e = t*8;                               // 512 thr x 8 shorts = one tile
    int e2 = e ^ (((e >> 6) & 7) << 3);
    int t0 = 2*pr, t1 = t0 + 1;
    gload_lds16(g_k + hoff + (size_t)(t0*64)*DK + e2, &ks[t0 & 3][e]);
    gload_lds16(g_k + hoff + (size_t)(t1*64)*DK + e2, &ks[t1 & 3][e]);
    gload_lds16(g_vt + hoff + (size_t)(e2 >> 6)*SEQ + t0*64 + (e2 & 63), &vs[t0 & 3][e]);
    gload_lds16(g_vt + hoff + (size_t)(e2 >> 6)*SEQ + t1*64 + (e2 & 63), &vs[t1 & 3][e]);
  };

  s16x8 qf[2][2];
  {
    const short* q0 = g_q + hoff + (size_t)(qbase + qg*32 + q15)*DK;
    qf[0][0] = *(const s16x8*)(q0 + g*8);
    qf[0][1] = *(const s16x8*)(q0 + 32 + g*8);
    qf[1][0] = *(const s16x8*)(q0 + 16*DK + g*8);
    qf[1][1] = *(const s16x8*)(q0 + 16*DK + 32 + g*8);
  }
  stage_pair(0);

  float lsum[2] = {0.f, 0.f};
  f32x4 o[2][4] = {};

  for (int i = 0; i < 16; ++i) {
    asm volatile("s_waitcnt vmcnt(0)" ::: "memory");
    __builtin_amdgcn_s_barrier();
    __builtin_amdgcn_sched_barrier(0);
    if (i + 1 < 16) stage_pair(i + 1);   // targets pair i-1's buffers (safe)

    const short* kb = ks[(2*i + kp) & 3];
    const short* vb = vs[(2*i + kp) & 3];

    f32x4 sc[2][4] = {};
    __builtin_amdgcn_s_setprio(1);
#pragma unroll
    for (int ni = 0; ni < 4; ++ni) {
      int row = ni*16 + q15;
      int sx = (row & 7) << 3;
      s16x8 k0 = *(const s16x8*)&kb[(row*64 + g*8) ^ sx];
      s16x8 k1 = *(const s16x8*)&kb[(row*64 + 32 + g*8) ^ sx];
      sc[0][ni] = mfma16(k0, qf[0][0], sc[0][ni]);
      sc[0][ni] = mfma16(k1, qf[0][1], sc[0][ni]);
      sc[1][ni] = mfma16(k0, qf[1][0], sc[1][ni]);
      sc[1][ni] = mfma16(k1, qf[1][1], sc[1][ni]);
    }
    __builtin_amdgcn_s_setprio(0);

    s16x8 pa[2][2];
#pragma unroll
    for (int grp = 0; grp < 2; ++grp) {
      float p[4][4];
#pragma unroll
      for (int ni = 0; ni < 4; ++ni)
#pragma unroll
        for (int r = 0; r < 4; ++r)
          p[ni][r] = fexp2(sc[grp][ni][r]);
      float s0 = (p[0][0]+p[0][1]) + (p[0][2]+p[0][3]);
      float s1 = (p[1][0]+p[1][1]) + (p[1][2]+p[1][3]);
      float s2 = (p[2][0]+p[2][1]) + (p[2][2]+p[2][3]);
      float s3 = (p[3][0]+p[3][1]) + (p[3][2]+p[3][3]);
      lsum[grp] += (s0+s1) + (s2+s3);

      unsigned pk[4][2];
#pragma unroll
      for (int ni = 0; ni < 4; ++ni) {
        pk[ni][0] = f2bf2(p[ni][0], p[ni][1]);
        pk[ni][1] = f2bf2(p[ni][2], p[ni][3]);
      }
#pragma unroll
      for (int kf = 0; kf < 2; ++kf) {
        u32x4 P4;
#pragma unroll
        for (int u = 0; u < 2; ++u) {
          unsigned x = pk[2*kf][u], y = pk[2*kf + 1][u];
          asm("v_permlane32_swap_b32 %0, %1" : "+v"(x), "+v"(y));
          asm("v_permlane16_swap_b32 %0, %1" : "+v"(x), "+v"(y));
          P4[u]     = x;
          P4[2 + u] = y;
        }
        union { u32x4 u4; s16x8 s8; } cv;
        cv.u4 = P4;
        pa[grp][kf] = cv.s8;
      }
    }

    __builtin_amdgcn_s_setprio(1);
#pragma unroll
    for (int nd = 0; nd < 4; ++nd) {
      int row = nd*16 + q15;
      int sx = (row & 7) << 3;
      s16x8 v0 = *(const s16x8*)&vb[(row*64 + g*8) ^ sx];
      s16x8 v1 = *(const s16x8*)&vb[(row*64 + 32 + g*8) ^ sx];
      o[0][nd] = mfma16(pa[0][0], v0, o[0][nd]);
      o[0][nd] = mfma16(pa[0][1], v1, o[0][nd]);
      o[1][nd] = mfma16(pa[1][0], v0, o[1][nd]);
      o[1][nd] = mfma16(pa[1][1], v1, o[1][nd]);
    }
    __builtin_amdgcn_s_setprio(0);
  }

  // ---- split-K combine ----
  __syncthreads();
  float* ob = (float*)&vs[0][0];
  float* lb = (float*)&ks[0][0];
  if (kp) {
#pragma unroll
    for (int grp = 0; grp < 2; ++grp) {
#pragma unroll
      for (int nd = 0; nd < 4; ++nd)
#pragma unroll
        for (int r = 0; r < 4; ++r)
          ob[(qg*32 + grp*16 + nd*4 + r)*64 + l] = o[grp][nd][r];
      lb[(qg*2 + grp)*64 + l] = lsum[grp];
    }
  }
  __syncthreads();
  if (!kp) {
    int b = bh >> 4, h = bh & 15;
#pragma unroll
    for (int grp = 0; grp < 2; ++grp) {
#pragma unroll
      for (int nd = 0; nd < 4; ++nd)
#pragma unroll
        for (int r = 0; r < 4; ++r)
          o[grp][nd][r] += ob[(qg*32 + grp*16 + nd*4 + r)*64 + l];
      float ls = lsum[grp] + lb[(qg*2 + grp)*64 + l];
      ls += __shfl_xor(ls, 16);
      ls += __shfl_xor(ls, 32);
      float inv = 1.0f / ls;
      float iv[4];
#pragma unroll
      for (int r = 0; r < 4; ++r)
        iv[r] = __shfl(inv, (l & 48) | (g*4 + r));
#pragma unroll
      for (int nd = 0; nd < 4; ++nd) {
        int dcol = h*DK + nd*16 + q15;
#pragma unroll
        for (int r = 0; r < 4; ++r) {
          int srow = qbase + qg*32 + grp*16 + g*4 + r;
          aout[((size_t)(b*SEQ + srow))*DMODEL + dcol] = f2bf(o[grp][nd][r] * iv[r]);
        }
      }
    }
  }
}

// ---------------- host side -------------------------------------------------
extern "C" void kernel_launch(void* const* d_in, const int* in_sizes, int n_in,
                              void* d_out, int out_size, void* d_ws, size_t ws_size,
                              hipStream_t stream) {
  const float* Q  = (const float*)d_in[0];
  const float* K  = (const float*)d_in[1];
  const float* V  = (const float*)d_in[2];
  const float* Wq = (const float*)d_in[3];
  const float* bq = (const float*)d_in[4];
  const float* Wk = (const float*)d_in[5];
  const float* bk = (const float*)d_in[6];
  const float* Wv = (const float*)d_in[7];
  const float* bv = (const float*)d_in[8];
  const float* Wo = (const float*)d_in[9];
  const float* bo = (const float*)d_in[10];

  short* pat;
  hipGetSymbolAddress((void**)&pat, HIP_SYMBOL(g_at));

  const int nX8 = MROWS*DMODEL/8;     // 524288
  dim3 blk(256);

  cast_all<<<dim3(nX8/256, 1, 7), blk, 0, stream>>>(Q, K, V, Wq, Wk, Wv, Wo);
  proj_qkv<<<dim3(8, 32, 3), blk, 0, stream>>>(bq, bk, bv);
  attn_kernel<<<dim3(SEQ/128, BATCH*NHEAD), dim3(512), 0, stream>>>(pat);
  proj_out<<<dim3(8, 32), blk, 0, stream>>>(bo, (float*)d_out);
}